// Round 2
// baseline (1807.624 us; speedup 1.0000x reference)
//
#include <hip/hip_runtime.h>
#include <hip/hip_bf16.h>

// Problem constants (from reference)
#define B_SZ 2
#define L_SZ 2048
#define DM   768
#define DI   1536
#define DTR  16
#define DS   16
#define DC   4
#define M_ROWS (B_SZ * L_SZ)   // 4096

static __device__ __forceinline__ float silu_f(float x) { return x / (1.f + __expf(-x)); }
static __device__ __forceinline__ float softplus_f(float x) {
  return x > 20.f ? x : log1pf(__expf(x));
}

// ---------------------------------------------------------------------------
// Tiled fp32 GEMM: C[M,N] = A[M,K] @ B[K,N], A,B fp32 row-major.
// 128x128 tile, 256 threads, 8x8 micro-tile, BK=8.
// EPI 0: split at col DI -> C0 = x_inner (fp32), C1 = silu(z) (fp32), both stride DI
// EPI 1: C0 fp32, stride N (col-guarded so N%128 != 0 is OK)
// ---------------------------------------------------------------------------
template <int EPI>
__global__ __launch_bounds__(256) void gemm_k(
    const float* __restrict__ Ap, const float* __restrict__ Bp,
    float* __restrict__ C0, float* __restrict__ C1,
    int M, int N, int K)
{
  __shared__ float As[8 * 128];
  __shared__ float Bs[8 * 128];
  const int tid = threadIdx.x;
  const int tx = tid & 15, ty = tid >> 4;
  const int brow = blockIdx.y << 7, bcol = blockIdx.x << 7;

  float acc[8][8];
#pragma unroll
  for (int i = 0; i < 8; ++i)
#pragma unroll
    for (int j = 0; j < 8; ++j) acc[i][j] = 0.f;

  // staging: A tile 128x8 (4 contiguous k per thread, transposed into As[k][row]),
  //          B tile 8x128 (4 contiguous cols per thread)
  const int ar = tid >> 1;            // 0..127 row within tile
  const int ak = (tid & 1) << 2;      // 0 or 4
  const int bk = tid >> 5;            // 0..7
  const int bc = (tid & 31) << 2;     // 0..124

  for (int k0 = 0; k0 < K; k0 += 8) {
    float4 avec = *reinterpret_cast<const float4*>(Ap + (size_t)(brow + ar) * K + k0 + ak);
    float4 bvec;
    if (bcol + bc < N) {
      bvec = *reinterpret_cast<const float4*>(Bp + (size_t)(k0 + bk) * N + bcol + bc);
    } else {
      bvec = make_float4(0.f, 0.f, 0.f, 0.f);
    }
    __syncthreads();   // previous iter's LDS reads done
    As[(ak + 0) * 128 + ar] = avec.x;
    As[(ak + 1) * 128 + ar] = avec.y;
    As[(ak + 2) * 128 + ar] = avec.z;
    As[(ak + 3) * 128 + ar] = avec.w;
    *reinterpret_cast<float4*>(&Bs[bk * 128 + bc]) = bvec;
    __syncthreads();
#pragma unroll
    for (int kk = 0; kk < 8; ++kk) {
      float4 a0 = *reinterpret_cast<const float4*>(&As[kk * 128 + (ty << 3)]);
      float4 a1 = *reinterpret_cast<const float4*>(&As[kk * 128 + (ty << 3) + 4]);
      float4 b0 = *reinterpret_cast<const float4*>(&Bs[kk * 128 + (tx << 3)]);
      float4 b1 = *reinterpret_cast<const float4*>(&Bs[kk * 128 + (tx << 3) + 4]);
      float a[8] = {a0.x, a0.y, a0.z, a0.w, a1.x, a1.y, a1.z, a1.w};
      float b[8] = {b0.x, b0.y, b0.z, b0.w, b1.x, b1.y, b1.z, b1.w};
#pragma unroll
      for (int i = 0; i < 8; ++i)
#pragma unroll
        for (int j = 0; j < 8; ++j) acc[i][j] = fmaf(a[i], b[j], acc[i][j]);
    }
  }

  const int row0 = brow + (ty << 3);
  const int col0 = bcol + (tx << 3);
#pragma unroll
  for (int i = 0; i < 8; ++i) {
#pragma unroll
    for (int j = 0; j < 8; ++j) {
      float v = acc[i][j];
      int r = row0 + i, c = col0 + j;
      if (EPI == 0) {
        if (c < DI) C0[(size_t)r * DI + c] = v;
        else        C1[(size_t)r * DI + (c - DI)] = silu_f(v);
      } else {
        if (c < N) C0[(size_t)r * N + c] = v;
      }
    }
  }
}

// ---------------------------------------------------------------------------
// Causal depthwise conv1d (kernel 4, left-pad 3, per-batch) + bias + silu
// layout: [B*L, DI] fp32
// ---------------------------------------------------------------------------
__global__ __launch_bounds__(256) void conv_silu_k(
    const float* __restrict__ xin, const float* __restrict__ w,
    const float* __restrict__ bias, float* __restrict__ xconv)
{
  int idx = blockIdx.x * 256 + threadIdx.x;      // over B*L*DI
  int d  = idx % DI;
  int bt = idx / DI;                             // b*L + t
  int t  = bt & (L_SZ - 1);
  float s = bias[d];
#pragma unroll
  for (int k = 0; k < DC; ++k) {
    int tt = t - (DC - 1) + k;
    if (tt >= 0)
      s = fmaf(w[d * DC + k], xin[(size_t)(bt - (DC - 1) + k) * DI + d], s);
  }
  xconv[idx] = silu_f(s);
}

// ---------------------------------------------------------------------------
// dt = softplus(x_dbl[:, :16] @ W_dt + b_dt)   (K = 16 -> dedicated kernel)
// ---------------------------------------------------------------------------
__global__ __launch_bounds__(256) void dtproj_k(
    const float* __restrict__ xdbl, const float* __restrict__ Wdt,
    const float* __restrict__ bdt, float* __restrict__ dtb)
{
  __shared__ float sx[DTR];
  int row = blockIdx.y;
  int d = blockIdx.x * 256 + threadIdx.x;
  if (threadIdx.x < DTR) sx[threadIdx.x] = xdbl[(size_t)row * 48 + threadIdx.x];
  __syncthreads();
  float s = bdt[d];
#pragma unroll
  for (int k = 0; k < DTR; ++k) s = fmaf(sx[k], Wdt[k * DI + d], s);
  dtb[(size_t)row * DI + d] = softplus_f(s);
}

// ---------------------------------------------------------------------------
// Selective scan: one thread per (b, d) channel; 16 states in registers.
// Fuses D-skip and z-gate; writes yz IN PLACE into z buffer.
// ---------------------------------------------------------------------------
__global__ __launch_bounds__(256) void scan_k(
    const float* __restrict__ xconv, const float* __restrict__ dtb,
    const float* __restrict__ xdbl, const float* __restrict__ Alog,
    const float* __restrict__ Dv, float* __restrict__ z_io)
{
  int tid = threadIdx.x;
  int b = blockIdx.x / (DI / 256);
  int d = (blockIdx.x % (DI / 256)) * 256 + tid;
  float Ar[DS];
#pragma unroll
  for (int n = 0; n < DS; ++n) Ar[n] = -__expf(Alog[d * DS + n]);
  float h[DS];
#pragma unroll
  for (int n = 0; n < DS; ++n) h[n] = 0.f;
  float Dd = Dv[d];
  size_t base = (size_t)b * L_SZ * DI + d;
  const float* xd = xdbl + (size_t)b * L_SZ * 48;
  for (int t = 0; t < L_SZ; ++t) {
    float u = xconv[base], dtv = dtb[base], zv = z_io[base];
    const float* bcp = xd + t * 48 + DTR;   // B then C, 16 each
    float du = dtv * u, y = 0.f;
#pragma unroll
    for (int n = 0; n < DS; ++n) {
      float dA = __expf(Ar[n] * dtv);
      h[n] = fmaf(h[n], dA, bcp[n] * du);
      y = fmaf(bcp[DS + n], h[n], y);
    }
    z_io[base] = (y + u * Dd) * zv;
    base += DI;
  }
}

// ---------------------------------------------------------------------------
extern "C" void kernel_launch(void* const* d_in, const int* in_sizes, int n_in,
                              void* d_out, int out_size, void* d_ws, size_t ws_size,
                              hipStream_t stream)
{
  const float* x      = (const float*)d_in[0];
  const float* W_in   = (const float*)d_in[1];
  const float* conv_w = (const float*)d_in[2];
  const float* conv_b = (const float*)d_in[3];
  const float* W_x    = (const float*)d_in[4];
  const float* W_dt   = (const float*)d_in[5];
  const float* b_dt   = (const float*)d_in[6];
  const float* A_log  = (const float*)d_in[7];
  const float* Dvec   = (const float*)d_in[8];
  const float* W_out  = (const float*)d_in[9];
  float* out = (float*)d_out;

  const size_t NBD = (size_t)M_ROWS * DI;   // 6,291,456 floats per [B*L, DI] buffer
  float* ws = (float*)d_ws;
  float* x_inner = ws;              // [B*L, DI]; reused as dt after conv consumes it
  float* z_buf   = ws + NBD;        // silu(z); scan overwrites in-place with yz
  float* x_conv  = ws + 2 * NBD;    // [B*L, DI]
  float* x_dbl   = ws + 3 * NBD;    // [B*L, 48]
  float* dt_buf  = x_inner;
  // total ws use: 3*NBD + 4096*48 floats ~ 76.3 MB

  // 1) xz = x @ W_in ; split + silu(z)
  gemm_k<0><<<dim3((2 * DI) / 128, M_ROWS / 128), 256, 0, stream>>>(
      x, W_in, x_inner, z_buf, M_ROWS, 2 * DI, DM);
  // 2) causal depthwise conv + bias + silu
  conv_silu_k<<<(int)(NBD / 256), 256, 0, stream>>>(x_inner, conv_w, conv_b, x_conv);
  // 3) x_dbl = x_conv @ W_x   (N = 48)
  gemm_k<1><<<dim3(1, M_ROWS / 128), 256, 0, stream>>>(
      x_conv, W_x, x_dbl, nullptr, M_ROWS, 48, DI);
  // 4) dt = softplus(dt_low @ W_dt + b_dt)
  dtproj_k<<<dim3(DI / 256, M_ROWS), 256, 0, stream>>>(x_dbl, W_dt, b_dt, dt_buf);
  // 5) selective scan + D-skip + z-gate (in place into z_buf)
  scan_k<<<B_SZ * (DI / 256), 256, 0, stream>>>(x_conv, dt_buf, x_dbl, A_log, Dvec, z_buf);
  // 6) out = yz @ W_out (fp32 store)
  gemm_k<1><<<dim3(DM / 128, M_ROWS / 128), 256, 0, stream>>>(
      z_buf, W_out, out, nullptr, M_ROWS, DM, DI);
}

// Round 3
// 970.976 us; speedup vs baseline: 1.8617x; 1.8617x over previous
//
#include <hip/hip_runtime.h>
#include <hip/hip_bf16.h>

// Problem constants (from reference)
#define B_SZ 2
#define L_SZ 2048
#define DM   768
#define DI   1536
#define DTR  16
#define DS   16
#define DC   4
#define M_ROWS (B_SZ * L_SZ)   // 4096
// chunked scan
#define CHUNK 64
#define NCH   (L_SZ / CHUNK)   // 32

static __device__ __forceinline__ float silu_f(float x) { return x / (1.f + __expf(-x)); }
static __device__ __forceinline__ float softplus_f(float x) {
  return x > 20.f ? x : log1pf(__expf(x));
}

// ---------------------------------------------------------------------------
// Tiled fp32 GEMM: C[M,N] = A[M,K] @ B[K,N], A,B fp32 row-major.
// 128x128 tile, 256 threads, 8x8 micro-tile, BK=8.
// EPI 0: split at col DI -> C0 = x_inner, C1 = silu(z), both stride DI
// EPI 1: C0 fp32, stride N (col-guarded so N%128 != 0 is OK)
// ---------------------------------------------------------------------------
template <int EPI>
__global__ __launch_bounds__(256) void gemm_k(
    const float* __restrict__ Ap, const float* __restrict__ Bp,
    float* __restrict__ C0, float* __restrict__ C1,
    int M, int N, int K)
{
  __shared__ float As[8 * 128];
  __shared__ float Bs[8 * 128];
  const int tid = threadIdx.x;
  const int tx = tid & 15, ty = tid >> 4;
  const int brow = blockIdx.y << 7, bcol = blockIdx.x << 7;

  float acc[8][8];
#pragma unroll
  for (int i = 0; i < 8; ++i)
#pragma unroll
    for (int j = 0; j < 8; ++j) acc[i][j] = 0.f;

  const int ar = tid >> 1;            // 0..127 row within tile
  const int ak = (tid & 1) << 2;      // 0 or 4
  const int bk = tid >> 5;            // 0..7
  const int bc = (tid & 31) << 2;     // 0..124

  for (int k0 = 0; k0 < K; k0 += 8) {
    float4 avec = *reinterpret_cast<const float4*>(Ap + (size_t)(brow + ar) * K + k0 + ak);
    float4 bvec;
    if (bcol + bc < N) {
      bvec = *reinterpret_cast<const float4*>(Bp + (size_t)(k0 + bk) * N + bcol + bc);
    } else {
      bvec = make_float4(0.f, 0.f, 0.f, 0.f);
    }
    __syncthreads();
    As[(ak + 0) * 128 + ar] = avec.x;
    As[(ak + 1) * 128 + ar] = avec.y;
    As[(ak + 2) * 128 + ar] = avec.z;
    As[(ak + 3) * 128 + ar] = avec.w;
    *reinterpret_cast<float4*>(&Bs[bk * 128 + bc]) = bvec;
    __syncthreads();
#pragma unroll
    for (int kk = 0; kk < 8; ++kk) {
      float4 a0 = *reinterpret_cast<const float4*>(&As[kk * 128 + (ty << 3)]);
      float4 a1 = *reinterpret_cast<const float4*>(&As[kk * 128 + (ty << 3) + 4]);
      float4 b0 = *reinterpret_cast<const float4*>(&Bs[kk * 128 + (tx << 3)]);
      float4 b1 = *reinterpret_cast<const float4*>(&Bs[kk * 128 + (tx << 3) + 4]);
      float a[8] = {a0.x, a0.y, a0.z, a0.w, a1.x, a1.y, a1.z, a1.w};
      float b[8] = {b0.x, b0.y, b0.z, b0.w, b1.x, b1.y, b1.z, b1.w};
#pragma unroll
      for (int i = 0; i < 8; ++i)
#pragma unroll
        for (int j = 0; j < 8; ++j) acc[i][j] = fmaf(a[i], b[j], acc[i][j]);
    }
  }

  const int row0 = brow + (ty << 3);
  const int col0 = bcol + (tx << 3);
#pragma unroll
  for (int i = 0; i < 8; ++i) {
#pragma unroll
    for (int j = 0; j < 8; ++j) {
      float v = acc[i][j];
      int r = row0 + i, c = col0 + j;
      if (EPI == 0) {
        if (c < DI) C0[(size_t)r * DI + c] = v;
        else        C1[(size_t)r * DI + (c - DI)] = silu_f(v);
      } else {
        if (c < N) C0[(size_t)r * N + c] = v;
      }
    }
  }
}

// ---------------------------------------------------------------------------
// Causal depthwise conv1d (kernel 4, left-pad 3, per-batch) + bias + silu
// ---------------------------------------------------------------------------
__global__ __launch_bounds__(256) void conv_silu_k(
    const float* __restrict__ xin, const float* __restrict__ w,
    const float* __restrict__ bias, float* __restrict__ xconv)
{
  int idx = blockIdx.x * 256 + threadIdx.x;      // over B*L*DI
  int d  = idx % DI;
  int bt = idx / DI;                             // b*L + t
  int t  = bt & (L_SZ - 1);
  float s = bias[d];
#pragma unroll
  for (int k = 0; k < DC; ++k) {
    int tt = t - (DC - 1) + k;
    if (tt >= 0)
      s = fmaf(w[d * DC + k], xin[(size_t)(bt - (DC - 1) + k) * DI + d], s);
  }
  xconv[idx] = silu_f(s);
}

// ---------------------------------------------------------------------------
// dt = softplus(x_dbl[:, :16] @ W_dt + b_dt)
// ---------------------------------------------------------------------------
__global__ __launch_bounds__(256) void dtproj_k(
    const float* __restrict__ xdbl, const float* __restrict__ Wdt,
    const float* __restrict__ bdt, float* __restrict__ dtb)
{
  __shared__ float sx[DTR];
  int row = blockIdx.y;
  int d = blockIdx.x * 256 + threadIdx.x;
  if (threadIdx.x < DTR) sx[threadIdx.x] = xdbl[(size_t)row * 48 + threadIdx.x];
  __syncthreads();
  float s = bdt[d];
#pragma unroll
  for (int k = 0; k < DTR; ++k) s = fmaf(sx[k], Wdt[k * DI + d], s);
  dtb[(size_t)row * DI + d] = softplus_f(s);
}

// ---------------------------------------------------------------------------
// Chunked selective scan, pass 1: per (b, chunk, d), scan from h0=0.
// Store decay products P[n] and local final state hF[n] at
//   agg[((b*NCH + chunk)*DI + d)*DS + n]   (= gid*DS + n)
// Blocks have uniform (b, chunk): DI % 256 == 0.
// ---------------------------------------------------------------------------
__global__ __launch_bounds__(256) void scan1_k(
    const float* __restrict__ xconv, const float* __restrict__ dtb,
    const float* __restrict__ xdbl, const float* __restrict__ Alog,
    float* __restrict__ hF, float* __restrict__ Pg)
{
  int gid = blockIdx.x * 256 + threadIdx.x;   // over B*NCH*DI
  int d = gid % DI;
  int bc = gid / DI;                          // b*NCH + chunk
  int chunk = bc % NCH;
  int b = bc / NCH;

  float Ar[DS];
#pragma unroll
  for (int n = 0; n < DS; ++n) Ar[n] = -__expf(Alog[d * DS + n]);
  float h[DS], P[DS];
#pragma unroll
  for (int n = 0; n < DS; ++n) { h[n] = 0.f; P[n] = 1.f; }

  size_t base = ((size_t)b * L_SZ + (size_t)chunk * CHUNK) * DI + d;
  const float* xd = xdbl + ((size_t)b * L_SZ + (size_t)chunk * CHUNK) * 48;
  for (int t = 0; t < CHUNK; ++t) {
    float u = xconv[base], dtv = dtb[base];
    float du = dtv * u;
    const float* bp = xd + t * 48 + DTR;      // B vector (16)
#pragma unroll
    for (int n = 0; n < DS; ++n) {
      float dA = __expf(Ar[n] * dtv);
      h[n] = fmaf(h[n], dA, bp[n] * du);
      P[n] *= dA;
    }
    base += DI;
  }
  size_t abase = (size_t)gid * DS;
#pragma unroll
  for (int n = 0; n < DS; ++n) { hF[abase + n] = h[n]; Pg[abase + n] = P[n]; }
}

// ---------------------------------------------------------------------------
// Pass 2: per (b, d, n) combine chunk aggregates sequentially.
// Overwrites hF in place with the chunk's INITIAL state h_in.
// ---------------------------------------------------------------------------
__global__ __launch_bounds__(256) void scan2_k(
    float* __restrict__ hF, const float* __restrict__ Pg)
{
  int gid = blockIdx.x * 256 + threadIdx.x;   // over B*DI*DS
  int b = gid / (DI * DS);
  int r = gid % (DI * DS);
  float carry = 0.f;
  for (int c = 0; c < NCH; ++c) {
    size_t idx = ((size_t)(b * NCH + c)) * (DI * DS) + r;
    float hf = hF[idx], p = Pg[idx];
    hF[idx] = carry;                          // h_in for this chunk
    carry = fmaf(p, carry, hf);
  }
}

// ---------------------------------------------------------------------------
// Pass 3: per (b, chunk, d), rescan from h_in, compute y, fuse D-skip + gate.
// Writes yz IN PLACE into z buffer.
// ---------------------------------------------------------------------------
__global__ __launch_bounds__(256) void scan3_k(
    const float* __restrict__ xconv, const float* __restrict__ dtb,
    const float* __restrict__ xdbl, const float* __restrict__ Alog,
    const float* __restrict__ hIn, const float* __restrict__ Dv,
    float* __restrict__ z_io)
{
  int gid = blockIdx.x * 256 + threadIdx.x;   // over B*NCH*DI
  int d = gid % DI;
  int bc = gid / DI;
  int chunk = bc % NCH;
  int b = bc / NCH;

  float Ar[DS];
#pragma unroll
  for (int n = 0; n < DS; ++n) Ar[n] = -__expf(Alog[d * DS + n]);
  float h[DS];
  size_t abase = (size_t)gid * DS;
#pragma unroll
  for (int n = 0; n < DS; ++n) h[n] = hIn[abase + n];
  float Dd = Dv[d];

  size_t base = ((size_t)b * L_SZ + (size_t)chunk * CHUNK) * DI + d;
  const float* xd = xdbl + ((size_t)b * L_SZ + (size_t)chunk * CHUNK) * 48;
  for (int t = 0; t < CHUNK; ++t) {
    float u = xconv[base], dtv = dtb[base], zv = z_io[base];
    float du = dtv * u, y = 0.f;
    const float* bcp = xd + t * 48 + DTR;     // B then C
#pragma unroll
    for (int n = 0; n < DS; ++n) {
      float dA = __expf(Ar[n] * dtv);
      h[n] = fmaf(h[n], dA, bcp[n] * du);
      y = fmaf(bcp[DS + n], h[n], y);
    }
    z_io[base] = (y + u * Dd) * zv;
    base += DI;
  }
}

// ---------------------------------------------------------------------------
extern "C" void kernel_launch(void* const* d_in, const int* in_sizes, int n_in,
                              void* d_out, int out_size, void* d_ws, size_t ws_size,
                              hipStream_t stream)
{
  const float* x      = (const float*)d_in[0];
  const float* W_in   = (const float*)d_in[1];
  const float* conv_w = (const float*)d_in[2];
  const float* conv_b = (const float*)d_in[3];
  const float* W_x    = (const float*)d_in[4];
  const float* W_dt   = (const float*)d_in[5];
  const float* b_dt   = (const float*)d_in[6];
  const float* A_log  = (const float*)d_in[7];
  const float* Dvec   = (const float*)d_in[8];
  const float* W_out  = (const float*)d_in[9];
  float* out = (float*)d_out;

  const size_t NBD = (size_t)M_ROWS * DI;     // 6,291,456 floats
  const size_t NAGG = (size_t)B_SZ * NCH * DI * DS;  // 1,572,864 floats
  float* ws = (float*)d_ws;
  float* x_inner = ws;                 // [B*L, DI]; reused as dt after conv
  float* z_buf   = ws + NBD;           // silu(z); scan3 overwrites with yz
  float* x_conv  = ws + 2 * NBD;       // [B*L, DI]
  float* x_dbl   = ws + 3 * NBD;       // [B*L, 48]
  float* hF      = x_dbl + (size_t)M_ROWS * 48;  // [B,NCH,DI,DS]
  float* Pg      = hF + NAGG;                    // [B,NCH,DI,DS]
  float* dt_buf  = x_inner;
  // total ws: 3*NBD + M*48 + 2*NAGG floats ~ 89 MB

  // 1) xz = x @ W_in ; split + silu(z)
  gemm_k<0><<<dim3((2 * DI) / 128, M_ROWS / 128), 256, 0, stream>>>(
      x, W_in, x_inner, z_buf, M_ROWS, 2 * DI, DM);
  // 2) causal depthwise conv + bias + silu
  conv_silu_k<<<(int)(NBD / 256), 256, 0, stream>>>(x_inner, conv_w, conv_b, x_conv);
  // 3) x_dbl = x_conv @ W_x   (N = 48)
  gemm_k<1><<<dim3(1, M_ROWS / 128), 256, 0, stream>>>(
      x_conv, W_x, x_dbl, nullptr, M_ROWS, 48, DI);
  // 4) dt = softplus(dt_low @ W_dt + b_dt)
  dtproj_k<<<dim3(DI / 256, M_ROWS), 256, 0, stream>>>(x_dbl, W_dt, b_dt, dt_buf);
  // 5) chunked selective scan (3 passes) + D-skip + z-gate in place
  scan1_k<<<B_SZ * NCH * DI / 256, 256, 0, stream>>>(x_conv, dt_buf, x_dbl, A_log, hF, Pg);
  scan2_k<<<B_SZ * DI * DS / 256, 256, 0, stream>>>(hF, Pg);
  scan3_k<<<B_SZ * NCH * DI / 256, 256, 0, stream>>>(x_conv, dt_buf, x_dbl, A_log, hF, Dvec, z_buf);
  // 6) out = yz @ W_out
  gemm_k<1><<<dim3(DM / 128, M_ROWS / 128), 256, 0, stream>>>(
      z_buf, W_out, out, nullptr, M_ROWS, DM, DI);
}

// Round 4
// 477.646 us; speedup vs baseline: 3.7844x; 2.0328x over previous
//
#include <hip/hip_runtime.h>
#include <hip/hip_bf16.h>

// Problem constants (from reference)
#define B_SZ 2
#define L_SZ 2048
#define DM   768
#define DI   1536
#define DTR  16
#define DS   16
#define DC   4
#define M_ROWS (B_SZ * L_SZ)   // 4096
// chunked scan
#define CHUNK 64
#define NCH   (L_SZ / CHUNK)   // 32

typedef unsigned short ushort_t;
typedef __attribute__((ext_vector_type(8))) short bf16x8;   // 8 bf16 (4 VGPRs)
typedef __attribute__((ext_vector_type(4))) float f32x4;

static __device__ __forceinline__ float silu_f(float x) { return x / (1.f + __expf(-x)); }
static __device__ __forceinline__ float softplus_f(float x) {
  return x > 20.f ? x : log1pf(__expf(x));
}
static __device__ __forceinline__ ushort_t f2bf(float f) {   // RNE
  union { float f; unsigned u; } v; v.f = f;
  unsigned r = v.u + 0x7fffu + ((v.u >> 16) & 1u);
  return (ushort_t)(r >> 16);
}

// async global->LDS, 16 B per lane; LDS dest = wave-uniform base + lane*16
static __device__ __forceinline__ void gld16(const void* g, void* l) {
  __builtin_amdgcn_global_load_lds(
      (const __attribute__((address_space(1))) void*)g,
      (__attribute__((address_space(3))) void*)l, 16, 0, 0);
}

// ---------------------------------------------------------------------------
// bf16 MFMA GEMM (BT): C[M,N] = A[M,K] @ Bt[N,K]^T, A/Bt bf16 row-major.
// 128x128 tile, 256 thr = 4 waves (2x2), wave = 64x64 = 4x4 frags 16x16x32.
// EPI 0: split at col DI -> C0 = x_inner (fp32), C1 = silu(z) (fp32), stride DI
// EPI 1: C0 fp32, stride N
// M,N % 128 == 0, K % 32 == 0.
// ---------------------------------------------------------------------------
template <int EPI>
__global__ __launch_bounds__(256) void mgemm_k(
    const ushort_t* __restrict__ A, const ushort_t* __restrict__ Bt,
    float* __restrict__ C0, float* __restrict__ C1, int M, int N, int K)
{
  __shared__ ushort_t As[128 * 32];   // [row][k] 8 KB
  __shared__ ushort_t Bs[128 * 32];   // [col][k] 8 KB
  const int tid = threadIdx.x;
  const int lane = tid & 63;
  const int wave = tid >> 6;
  const int quad = lane >> 4, lr = lane & 15;
  const int wr = wave >> 1, wc = wave & 1;
  const int brow = blockIdx.y << 7, bcol = blockIdx.x << 7;

  f32x4 acc[4][4];
#pragma unroll
  for (int i = 0; i < 4; ++i)
#pragma unroll
    for (int j = 0; j < 4; ++j) acc[i][j] = (f32x4){0.f, 0.f, 0.f, 0.f};

  const int srow = tid >> 2;            // 0..63: tile row (first 64)
  const int sseg = (tid & 3) << 3;      // k offset 0,8,16,24

  for (int k0 = 0; k0 < K; k0 += 32) {
    const ushort_t* ga0 = A  + (size_t)(brow + srow)      * K + k0 + sseg;
    const ushort_t* ga1 = A  + (size_t)(brow + 64 + srow) * K + k0 + sseg;
    const ushort_t* gb0 = Bt + (size_t)(bcol + srow)      * K + k0 + sseg;
    const ushort_t* gb1 = Bt + (size_t)(bcol + 64 + srow) * K + k0 + sseg;
    gld16(ga0, &As[tid * 8]);
    gld16(ga1, &As[2048 + tid * 8]);
    gld16(gb0, &Bs[tid * 8]);
    gld16(gb1, &Bs[2048 + tid * 8]);
    __builtin_amdgcn_s_waitcnt(0);      // drain vmcnt (global_load_lds)
    __syncthreads();

    bf16x8 af[4], bf[4];
#pragma unroll
    for (int i = 0; i < 4; ++i)
      af[i] = *reinterpret_cast<const bf16x8*>(&As[(wr * 64 + i * 16 + lr) * 32 + quad * 8]);
#pragma unroll
    for (int j = 0; j < 4; ++j)
      bf[j] = *reinterpret_cast<const bf16x8*>(&Bs[(wc * 64 + j * 16 + lr) * 32 + quad * 8]);
#pragma unroll
    for (int i = 0; i < 4; ++i)
#pragma unroll
      for (int j = 0; j < 4; ++j)
        acc[i][j] = __builtin_amdgcn_mfma_f32_16x16x32_bf16(af[i], bf[j], acc[i][j], 0, 0, 0);
    __syncthreads();
  }

  // C/D layout: col = lane&15, row = quad*4 + reg  [verified m89/m91]
#pragma unroll
  for (int i = 0; i < 4; ++i) {
#pragma unroll
    for (int j = 0; j < 4; ++j) {
#pragma unroll
      for (int r = 0; r < 4; ++r) {
        int row = brow + wr * 64 + i * 16 + quad * 4 + r;
        int col = bcol + wc * 64 + j * 16 + lr;
        float v = acc[i][j][r];
        if (EPI == 0) {
          if (col < DI) C0[(size_t)row * DI + col] = v;
          else          C1[(size_t)row * DI + (col - DI)] = silu_f(v);
        } else {
          C0[(size_t)row * N + col] = v;
        }
      }
    }
  }
}

// ---------------------------------------------------------------------------
// fp32 -> bf16 convert (vectorized x4); n % 1024 == 0
// ---------------------------------------------------------------------------
__global__ __launch_bounds__(256) void cvt4_k(
    const float* __restrict__ in, ushort_t* __restrict__ out)
{
  int i = blockIdx.x * 256 + threadIdx.x;
  float4 v = reinterpret_cast<const float4*>(in)[i];
  ushort4 o;
  o.x = f2bf(v.x); o.y = f2bf(v.y); o.z = f2bf(v.z); o.w = f2bf(v.w);
  reinterpret_cast<ushort4*>(out)[i] = o;
}

// ---------------------------------------------------------------------------
// transpose + convert: T[c][r] = bf16(S[r][c]); R,C % 32 == 0
// ---------------------------------------------------------------------------
__global__ __launch_bounds__(256) void tcvt_k(
    const float* __restrict__ S, ushort_t* __restrict__ T, int R, int C)
{
  __shared__ float tile[32][33];
  const int c0 = blockIdx.x << 5, r0 = blockIdx.y << 5;
  const int tx = threadIdx.x & 31, ty = threadIdx.x >> 5;   // 32 x 8
  for (int rr = ty; rr < 32; rr += 8)
    tile[rr][tx] = S[(size_t)(r0 + rr) * C + c0 + tx];
  __syncthreads();
  for (int cc = ty; cc < 32; cc += 8)
    T[(size_t)(c0 + cc) * R + r0 + tx] = f2bf(tile[tx][cc]);
}

// ---------------------------------------------------------------------------
// Causal depthwise conv1d (kernel 4, left-pad 3, per-batch) + bias + silu
// ---------------------------------------------------------------------------
__global__ __launch_bounds__(256) void conv_silu_k(
    const float* __restrict__ xin, const float* __restrict__ w,
    const float* __restrict__ bias, float* __restrict__ xconv)
{
  int idx = blockIdx.x * 256 + threadIdx.x;      // over B*L*DI
  int d  = idx % DI;
  int bt = idx / DI;                             // b*L + t
  int t  = bt & (L_SZ - 1);
  float s = bias[d];
#pragma unroll
  for (int k = 0; k < DC; ++k) {
    int tt = t - (DC - 1) + k;
    if (tt >= 0)
      s = fmaf(w[d * DC + k], xin[(size_t)(bt - (DC - 1) + k) * DI + d], s);
  }
  xconv[idx] = silu_f(s);
}

// ---------------------------------------------------------------------------
// x_dbl[M,48] = x_conv[M,DI] @ Wx[DI,48] — one wave per row, fp32.
// ---------------------------------------------------------------------------
__global__ __launch_bounds__(256) void xdbl_k(
    const float* __restrict__ xc, const float* __restrict__ Wx,
    float* __restrict__ xdbl)
{
  __shared__ float srow[4][128];
  const int wave = threadIdx.x >> 6, lane = threadIdx.x & 63;
  const int row = (blockIdx.x << 2) + wave;
  const float* a = xc + (size_t)row * DI;
  float acc = 0.f;
  for (int k0 = 0; k0 < DI; k0 += 128) {
    if (lane < 32)
      *reinterpret_cast<float4*>(&srow[wave][lane << 2]) =
          *reinterpret_cast<const float4*>(a + k0 + (lane << 2));
    __syncthreads();
    if (lane < 48) {
#pragma unroll 4
      for (int kk = 0; kk < 128; ++kk)
        acc = fmaf(srow[wave][kk], Wx[(size_t)(k0 + kk) * 48 + lane], acc);
    }
    __syncthreads();
  }
  if (lane < 48) xdbl[(size_t)row * 48 + lane] = acc;
}

// ---------------------------------------------------------------------------
// dt = softplus(x_dbl[:, :16] @ W_dt + b_dt)
// ---------------------------------------------------------------------------
__global__ __launch_bounds__(256) void dtproj_k(
    const float* __restrict__ xdbl, const float* __restrict__ Wdt,
    const float* __restrict__ bdt, float* __restrict__ dtb)
{
  __shared__ float sx[DTR];
  int row = blockIdx.y;
  int d = blockIdx.x * 256 + threadIdx.x;
  if (threadIdx.x < DTR) sx[threadIdx.x] = xdbl[(size_t)row * 48 + threadIdx.x];
  __syncthreads();
  float s = bdt[d];
#pragma unroll
  for (int k = 0; k < DTR; ++k) s = fmaf(sx[k], Wdt[k * DI + d], s);
  dtb[(size_t)row * DI + d] = softplus_f(s);
}

// ---------------------------------------------------------------------------
// Chunked selective scan, pass 1: per (b, chunk, d), scan from h0=0.
// ---------------------------------------------------------------------------
__global__ __launch_bounds__(256) void scan1_k(
    const float* __restrict__ xconv, const float* __restrict__ dtb,
    const float* __restrict__ xdbl, const float* __restrict__ Alog,
    float* __restrict__ hF, float* __restrict__ Pg)
{
  int gid = blockIdx.x * 256 + threadIdx.x;   // over B*NCH*DI
  int d = gid % DI;
  int bc = gid / DI;
  int chunk = bc % NCH;
  int b = bc / NCH;

  float Ar[DS];
#pragma unroll
  for (int n = 0; n < DS; ++n) Ar[n] = -__expf(Alog[d * DS + n]);
  float h[DS], P[DS];
#pragma unroll
  for (int n = 0; n < DS; ++n) { h[n] = 0.f; P[n] = 1.f; }

  size_t base = ((size_t)b * L_SZ + (size_t)chunk * CHUNK) * DI + d;
  const float* xd = xdbl + ((size_t)b * L_SZ + (size_t)chunk * CHUNK) * 48;
  for (int t = 0; t < CHUNK; ++t) {
    float u = xconv[base], dtv = dtb[base];
    float du = dtv * u;
    const float* bp = xd + t * 48 + DTR;
#pragma unroll
    for (int n = 0; n < DS; ++n) {
      float dA = __expf(Ar[n] * dtv);
      h[n] = fmaf(h[n], dA, bp[n] * du);
      P[n] *= dA;
    }
    base += DI;
  }
  size_t abase = (size_t)gid * DS;
#pragma unroll
  for (int n = 0; n < DS; ++n) { hF[abase + n] = h[n]; Pg[abase + n] = P[n]; }
}

// ---------------------------------------------------------------------------
// Pass 2: per (b, d, n) combine chunk aggregates; hF <- chunk INITIAL state.
// ---------------------------------------------------------------------------
__global__ __launch_bounds__(256) void scan2_k(
    float* __restrict__ hF, const float* __restrict__ Pg)
{
  int gid = blockIdx.x * 256 + threadIdx.x;   // over B*DI*DS
  int b = gid / (DI * DS);
  int r = gid % (DI * DS);
  float carry = 0.f;
  for (int c = 0; c < NCH; ++c) {
    size_t idx = ((size_t)(b * NCH + c)) * (DI * DS) + r;
    float hf = hF[idx], p = Pg[idx];
    hF[idx] = carry;
    carry = fmaf(p, carry, hf);
  }
}

// ---------------------------------------------------------------------------
// Pass 3: rescan from h_in; fuse D-skip + z-gate; emit yz as bf16 for out_proj.
// ---------------------------------------------------------------------------
__global__ __launch_bounds__(256) void scan3_k(
    const float* __restrict__ xconv, const float* __restrict__ dtb,
    const float* __restrict__ xdbl, const float* __restrict__ Alog,
    const float* __restrict__ hIn, const float* __restrict__ Dv,
    const float* __restrict__ z_in, ushort_t* __restrict__ yzb)
{
  int gid = blockIdx.x * 256 + threadIdx.x;   // over B*NCH*DI
  int d = gid % DI;
  int bc = gid / DI;
  int chunk = bc % NCH;
  int b = bc / NCH;

  float Ar[DS];
#pragma unroll
  for (int n = 0; n < DS; ++n) Ar[n] = -__expf(Alog[d * DS + n]);
  float h[DS];
  size_t abase = (size_t)gid * DS;
#pragma unroll
  for (int n = 0; n < DS; ++n) h[n] = hIn[abase + n];
  float Dd = Dv[d];

  size_t base = ((size_t)b * L_SZ + (size_t)chunk * CHUNK) * DI + d;
  const float* xd = xdbl + ((size_t)b * L_SZ + (size_t)chunk * CHUNK) * 48;
  for (int t = 0; t < CHUNK; ++t) {
    float u = xconv[base], dtv = dtb[base], zv = z_in[base];
    float du = dtv * u, y = 0.f;
    const float* bcp = xd + t * 48 + DTR;
#pragma unroll
    for (int n = 0; n < DS; ++n) {
      float dA = __expf(Ar[n] * dtv);
      h[n] = fmaf(h[n], dA, bcp[n] * du);
      y = fmaf(bcp[DS + n], h[n], y);
    }
    yzb[base] = f2bf((y + u * Dd) * zv);
    base += DI;
  }
}

// ---------------------------------------------------------------------------
extern "C" void kernel_launch(void* const* d_in, const int* in_sizes, int n_in,
                              void* d_out, int out_size, void* d_ws, size_t ws_size,
                              hipStream_t stream)
{
  const float* x      = (const float*)d_in[0];
  const float* W_in   = (const float*)d_in[1];
  const float* conv_w = (const float*)d_in[2];
  const float* conv_b = (const float*)d_in[3];
  const float* W_x    = (const float*)d_in[4];
  const float* W_dt   = (const float*)d_in[5];
  const float* b_dt   = (const float*)d_in[6];
  const float* A_log  = (const float*)d_in[7];
  const float* Dvec   = (const float*)d_in[8];
  const float* W_out  = (const float*)d_in[9];
  float* out = (float*)d_out;

  const size_t NBD  = (size_t)M_ROWS * DI;           // 6,291,456
  const size_t NAGG = (size_t)B_SZ * NCH * DI * DS;  // 1,572,864
  float* ws = (float*)d_ws;
  float* x_inner = ws;                 // [M, DI]; reused as dt after conv
  float* z_buf   = ws + NBD;           // silu(z)
  float* x_conv  = ws + 2 * NBD;       // [M, DI]
  float* x_dbl   = ws + 3 * NBD;       // [M, 48]
  float* hF      = x_dbl + (size_t)M_ROWS * 64;      // [B,NCH,DI,DS] (64 pads 48)
  float* Pg      = hF + NAGG;
  float* fend    = Pg + NAGG;
  ushort_t* xb     = (ushort_t*)fend;                          // [M, DM] bf16
  ushort_t* Wb_in  = xb    + (size_t)M_ROWS * DM;              // [2DI, DM] bf16 (W_in^T)
  ushort_t* Wb_out = Wb_in + (size_t)DM * 2 * DI;              // [DM, DI] bf16 (W_out^T)
  ushort_t* yzb    = Wb_out + (size_t)DI * DM;                 // [M, DI] bf16
  float* dt_buf  = x_inner;
  // total ws ~ 115 MB

  // 0) precision prep: x -> bf16; W_in, W_out -> transposed bf16
  cvt4_k<<<(int)((size_t)M_ROWS * DM / 1024), 256, 0, stream>>>(x, xb);
  tcvt_k<<<dim3((2 * DI) / 32, DM / 32), 256, 0, stream>>>(W_in, Wb_in, DM, 2 * DI);
  tcvt_k<<<dim3(DM / 32, DI / 32), 256, 0, stream>>>(W_out, Wb_out, DI, DM);
  // 1) xz = x @ W_in ; split + silu(z)  [bf16 MFMA]
  mgemm_k<0><<<dim3((2 * DI) / 128, M_ROWS / 128), 256, 0, stream>>>(
      xb, Wb_in, x_inner, z_buf, M_ROWS, 2 * DI, DM);
  // 2) causal depthwise conv + bias + silu
  conv_silu_k<<<(int)(NBD / 256), 256, 0, stream>>>(x_inner, conv_w, conv_b, x_conv);
  // 3) x_dbl = x_conv @ W_x (fp32, wave-per-row)
  xdbl_k<<<M_ROWS / 4, 256, 0, stream>>>(x_conv, W_x, x_dbl);
  // 4) dt = softplus(dt_low @ W_dt + b_dt)
  dtproj_k<<<dim3(DI / 256, M_ROWS), 256, 0, stream>>>(x_dbl, W_dt, b_dt, dt_buf);
  // 5) chunked selective scan (3 passes); scan3 emits yz bf16
  scan1_k<<<B_SZ * NCH * DI / 256, 256, 0, stream>>>(x_conv, dt_buf, x_dbl, A_log, hF, Pg);
  scan2_k<<<B_SZ * DI * DS / 256, 256, 0, stream>>>(hF, Pg);
  scan3_k<<<B_SZ * NCH * DI / 256, 256, 0, stream>>>(
      x_conv, dt_buf, x_dbl, A_log, hF, Dvec, z_buf, yzb);
  // 6) out = yz @ W_out  [bf16 MFMA]
  mgemm_k<1><<<dim3(DM / 128, M_ROWS / 128), 256, 0, stream>>>(
      yzb, Wb_out, out, nullptr, M_ROWS, DM, DI);
}

// Round 5
// 357.738 us; speedup vs baseline: 5.0529x; 1.3352x over previous
//
#include <hip/hip_runtime.h>
#include <hip/hip_bf16.h>

// Problem constants (from reference)
#define B_SZ 2
#define L_SZ 2048
#define DM   768
#define DI   1536
#define DTR  16
#define DS   16
#define DC   4
#define M_ROWS (B_SZ * L_SZ)   // 4096
// chunked scan
#define CHUNK 64
#define NCH   (L_SZ / CHUNK)   // 32
#define KSPLIT 8
#define KSEG  (DI / KSPLIT)    // 192

typedef unsigned short ushort_t;
typedef __attribute__((ext_vector_type(8))) short bf16x8;   // 8 bf16 (4 VGPRs)
typedef __attribute__((ext_vector_type(4))) float f32x4;

static __device__ __forceinline__ float silu_f(float x) { return x / (1.f + __expf(-x)); }
static __device__ __forceinline__ float softplus_f(float x) {
  return x > 20.f ? x : log1pf(__expf(x));
}
static __device__ __forceinline__ ushort_t f2bf(float f) {   // RNE
  union { float f; unsigned u; } v; v.f = f;
  unsigned r = v.u + 0x7fffu + ((v.u >> 16) & 1u);
  return (ushort_t)(r >> 16);
}

// async global->LDS, 16 B per lane; LDS dest = wave-uniform base + lane*16
static __device__ __forceinline__ void gld16(const void* g, void* l) {
  __builtin_amdgcn_global_load_lds(
      (const __attribute__((address_space(1))) void*)g,
      (__attribute__((address_space(3))) void*)l, 16, 0, 0);
}

// ---------------------------------------------------------------------------
// bf16 MFMA GEMM (BT): C[M,N] = A[M,K] @ Bt[N,K]^T, A/Bt bf16 row-major.
// 128x128 tile, 256 thr = 4 waves (2x2), wave = 64x64 = 4x4 frags 16x16x32.
// EPI 0: split at col DI -> C0 = x_inner (fp32), C1 = silu(z) (fp32), stride DI
// EPI 1: C0 fp32, stride N
// ---------------------------------------------------------------------------
template <int EPI>
__global__ __launch_bounds__(256) void mgemm_k(
    const ushort_t* __restrict__ A, const ushort_t* __restrict__ Bt,
    float* __restrict__ C0, float* __restrict__ C1, int M, int N, int K)
{
  __shared__ ushort_t As[128 * 32];   // [row][k] 8 KB
  __shared__ ushort_t Bs[128 * 32];   // [col][k] 8 KB
  const int tid = threadIdx.x;
  const int lane = tid & 63;
  const int wave = tid >> 6;
  const int quad = lane >> 4, lr = lane & 15;
  const int wr = wave >> 1, wc = wave & 1;
  const int brow = blockIdx.y << 7, bcol = blockIdx.x << 7;

  f32x4 acc[4][4];
#pragma unroll
  for (int i = 0; i < 4; ++i)
#pragma unroll
    for (int j = 0; j < 4; ++j) acc[i][j] = (f32x4){0.f, 0.f, 0.f, 0.f};

  const int srow = tid >> 2;            // 0..63: tile row (first 64)
  const int sseg = (tid & 3) << 3;      // k offset 0,8,16,24

  for (int k0 = 0; k0 < K; k0 += 32) {
    const ushort_t* ga0 = A  + (size_t)(brow + srow)      * K + k0 + sseg;
    const ushort_t* ga1 = A  + (size_t)(brow + 64 + srow) * K + k0 + sseg;
    const ushort_t* gb0 = Bt + (size_t)(bcol + srow)      * K + k0 + sseg;
    const ushort_t* gb1 = Bt + (size_t)(bcol + 64 + srow) * K + k0 + sseg;
    gld16(ga0, &As[tid * 8]);
    gld16(ga1, &As[2048 + tid * 8]);
    gld16(gb0, &Bs[tid * 8]);
    gld16(gb1, &Bs[2048 + tid * 8]);
    __builtin_amdgcn_s_waitcnt(0);      // drain vmcnt (global_load_lds)
    __syncthreads();

    bf16x8 af[4], bf[4];
#pragma unroll
    for (int i = 0; i < 4; ++i)
      af[i] = *reinterpret_cast<const bf16x8*>(&As[(wr * 64 + i * 16 + lr) * 32 + quad * 8]);
#pragma unroll
    for (int j = 0; j < 4; ++j)
      bf[j] = *reinterpret_cast<const bf16x8*>(&Bs[(wc * 64 + j * 16 + lr) * 32 + quad * 8]);
#pragma unroll
    for (int i = 0; i < 4; ++i)
#pragma unroll
      for (int j = 0; j < 4; ++j)
        acc[i][j] = __builtin_amdgcn_mfma_f32_16x16x32_bf16(af[i], bf[j], acc[i][j], 0, 0, 0);
    __syncthreads();
  }

  // C/D layout: col = lane&15, row = quad*4 + reg  [verified m89/m91]
#pragma unroll
  for (int i = 0; i < 4; ++i) {
#pragma unroll
    for (int j = 0; j < 4; ++j) {
#pragma unroll
      for (int r = 0; r < 4; ++r) {
        int row = brow + wr * 64 + i * 16 + quad * 4 + r;
        int col = bcol + wc * 64 + j * 16 + lr;
        float v = acc[i][j][r];
        if (EPI == 0) {
          if (col < DI) C0[(size_t)row * DI + col] = v;
          else          C1[(size_t)row * DI + (col - DI)] = silu_f(v);
        } else {
          C0[(size_t)row * N + col] = v;
        }
      }
    }
  }
}

// ---------------------------------------------------------------------------
// fp32 -> bf16 convert (vectorized x4); n % 1024 == 0
// ---------------------------------------------------------------------------
__global__ __launch_bounds__(256) void cvt4_k(
    const float* __restrict__ in, ushort_t* __restrict__ out)
{
  int i = blockIdx.x * 256 + threadIdx.x;
  float4 v = reinterpret_cast<const float4*>(in)[i];
  ushort4 o;
  o.x = f2bf(v.x); o.y = f2bf(v.y); o.z = f2bf(v.z); o.w = f2bf(v.w);
  reinterpret_cast<ushort4*>(out)[i] = o;
}

// ---------------------------------------------------------------------------
// transpose + convert: T[c][r] = bf16(S[r][c]); R,C % 32 == 0
// ---------------------------------------------------------------------------
__global__ __launch_bounds__(256) void tcvt_k(
    const float* __restrict__ S, ushort_t* __restrict__ T, int R, int C)
{
  __shared__ float tile[32][33];
  const int c0 = blockIdx.x << 5, r0 = blockIdx.y << 5;
  const int tx = threadIdx.x & 31, ty = threadIdx.x >> 5;   // 32 x 8
  for (int rr = ty; rr < 32; rr += 8)
    tile[rr][tx] = S[(size_t)(r0 + rr) * C + c0 + tx];
  __syncthreads();
  for (int cc = ty; cc < 32; cc += 8)
    T[(size_t)(c0 + cc) * R + r0 + tx] = f2bf(tile[tx][cc]);
}

// ---------------------------------------------------------------------------
// W_x [DI,48] -> Wxb [64, DI] bf16 transposed, rows 48..63 zero
// ---------------------------------------------------------------------------
__global__ __launch_bounds__(256) void wxcvt_k(
    const float* __restrict__ Wx, ushort_t* __restrict__ Wxb)
{
  int gid = blockIdx.x * 256 + threadIdx.x;   // over 64*DI
  int k = gid % DI, n = gid / DI;
  Wxb[gid] = (n < 48) ? f2bf(Wx[(size_t)k * 48 + n]) : (ushort_t)0;
}

// ---------------------------------------------------------------------------
// Causal depthwise conv1d (k=4, left-pad 3, per-batch) + bias + silu.
// Vectorized x4 over d. Emits fp32 x_conv (for scan) AND bf16 xcb (for x_dbl GEMM).
// ---------------------------------------------------------------------------
__global__ __launch_bounds__(256) void conv_silu_k(
    const float* __restrict__ xin, const float* __restrict__ w,
    const float* __restrict__ bias, float* __restrict__ xconv,
    ushort_t* __restrict__ xcb)
{
  int idx = blockIdx.x * 256 + threadIdx.x;      // over B*L*DI/4
  int d4 = (idx % (DI / 4)) << 2;
  int bt = idx / (DI / 4);                       // b*L + t
  int t  = bt & (L_SZ - 1);
  float s[4];
  {
    float4 bv = *reinterpret_cast<const float4*>(&bias[d4]);
    s[0] = bv.x; s[1] = bv.y; s[2] = bv.z; s[3] = bv.w;
  }
  float wt[4][4];
#pragma unroll
  for (int c = 0; c < 4; ++c) {
    float4 wv = *reinterpret_cast<const float4*>(&w[(d4 + c) * DC]);
    wt[c][0] = wv.x; wt[c][1] = wv.y; wt[c][2] = wv.z; wt[c][3] = wv.w;
  }
#pragma unroll
  for (int k = 0; k < DC; ++k) {
    int tt = t - (DC - 1) + k;
    if (tt >= 0) {
      float4 xv = *reinterpret_cast<const float4*>(
          &xin[(size_t)(bt - (DC - 1) + k) * DI + d4]);
      s[0] = fmaf(wt[0][k], xv.x, s[0]);
      s[1] = fmaf(wt[1][k], xv.y, s[1]);
      s[2] = fmaf(wt[2][k], xv.z, s[2]);
      s[3] = fmaf(wt[3][k], xv.w, s[3]);
    }
  }
  float4 o;
  o.x = silu_f(s[0]); o.y = silu_f(s[1]); o.z = silu_f(s[2]); o.w = silu_f(s[3]);
  reinterpret_cast<float4*>(xconv)[idx] = o;
  ushort4 ob;
  ob.x = f2bf(o.x); ob.y = f2bf(o.y); ob.z = f2bf(o.z); ob.w = f2bf(o.w);
  reinterpret_cast<ushort4*>(xcb)[idx] = ob;
}

// ---------------------------------------------------------------------------
// x_dbl split-K MFMA: psum[split][M][48] = xcb[:, kseg] @ Wxb[0:48, kseg]^T
// Block: 64 rows x 48 cols, 4 waves (16 rows each), KSEG=192 per split.
// ---------------------------------------------------------------------------
__global__ __launch_bounds__(256) void xdbl_mfma_k(
    const ushort_t* __restrict__ A, const ushort_t* __restrict__ Bt,
    float* __restrict__ psum)
{
  __shared__ ushort_t As[64 * 32];   // 4 KB: [row][k]
  __shared__ ushort_t Bs[64 * 32];   // 4 KB: [col][k] (cols 48..63 are zero pad)
  const int tid = threadIdx.x, lane = tid & 63, wv = tid >> 6;
  const int quad = lane >> 4, lr = lane & 15;
  const int brow = blockIdx.x << 6;
  const int kbase = blockIdx.y * KSEG;

  f32x4 acc[3];
#pragma unroll
  for (int j = 0; j < 3; ++j) acc[j] = (f32x4){0.f, 0.f, 0.f, 0.f};

  const int srow = tid >> 2, sseg = (tid & 3) << 3;
  for (int k0 = 0; k0 < KSEG; k0 += 32) {
    gld16(A + (size_t)(brow + srow) * DI + kbase + k0 + sseg, &As[tid * 8]);
    gld16(Bt + (size_t)srow * DI + kbase + k0 + sseg, &Bs[tid * 8]);
    __builtin_amdgcn_s_waitcnt(0);
    __syncthreads();
    bf16x8 af = *reinterpret_cast<const bf16x8*>(&As[(wv * 16 + lr) * 32 + quad * 8]);
#pragma unroll
    for (int j = 0; j < 3; ++j) {
      bf16x8 bf = *reinterpret_cast<const bf16x8*>(&Bs[(j * 16 + lr) * 32 + quad * 8]);
      acc[j] = __builtin_amdgcn_mfma_f32_16x16x32_bf16(af, bf, acc[j], 0, 0, 0);
    }
    __syncthreads();
  }
#pragma unroll
  for (int j = 0; j < 3; ++j) {
#pragma unroll
    for (int r = 0; r < 4; ++r) {
      int row = brow + wv * 16 + quad * 4 + r;
      int col = j * 16 + lr;
      psum[((size_t)blockIdx.y * M_ROWS + row) * 48 + col] = acc[j][r];
    }
  }
}

__global__ __launch_bounds__(256) void xdbl_reduce_k(
    const float* __restrict__ psum, float* __restrict__ xdbl)
{
  int gid = blockIdx.x * 256 + threadIdx.x;   // over M*48
  float s = 0.f;
#pragma unroll
  for (int i = 0; i < KSPLIT; ++i) s += psum[(size_t)i * M_ROWS * 48 + gid];
  xdbl[gid] = s;
}

// ---------------------------------------------------------------------------
// Chunked selective scan, pass 1: per (b, chunk, d), scan from h0=0.
// dt_proj FUSED: dt = softplus(x_dbl[row, 0:16] . W_dt[:, d] + b_dt[d]).
// ---------------------------------------------------------------------------
__global__ __launch_bounds__(256) void scan1_k(
    const float* __restrict__ xconv, const float* __restrict__ xdbl,
    const float* __restrict__ Alog, const float* __restrict__ Wdt,
    const float* __restrict__ bdt, float* __restrict__ hF, float* __restrict__ Pg)
{
  int gid = blockIdx.x * 256 + threadIdx.x;   // over B*NCH*DI
  int d = gid % DI;
  int bc = gid / DI;
  int chunk = bc % NCH;
  int b = bc / NCH;

  float Ar[DS], Wc[DTR];
#pragma unroll
  for (int n = 0; n < DS; ++n) Ar[n] = -__expf(Alog[d * DS + n]);
#pragma unroll
  for (int k = 0; k < DTR; ++k) Wc[k] = Wdt[k * DI + d];
  float bd = bdt[d];
  float h[DS], P[DS];
#pragma unroll
  for (int n = 0; n < DS; ++n) { h[n] = 0.f; P[n] = 1.f; }

  size_t base = ((size_t)b * L_SZ + (size_t)chunk * CHUNK) * DI + d;
  const float* xd = xdbl + ((size_t)b * L_SZ + (size_t)chunk * CHUNK) * 48;
  for (int t = 0; t < CHUNK; ++t) {
    const float* xr = xd + t * 48;
    float dta = bd;
#pragma unroll
    for (int k = 0; k < DTR; ++k) dta = fmaf(xr[k], Wc[k], dta);
    float dtv = softplus_f(dta);
    float u = xconv[base];
    float du = dtv * u;
#pragma unroll
    for (int n = 0; n < DS; ++n) {
      float dA = __expf(Ar[n] * dtv);
      h[n] = fmaf(h[n], dA, xr[DTR + n] * du);
      P[n] *= dA;
    }
    base += DI;
  }
  size_t abase = (size_t)gid * DS;
#pragma unroll
  for (int n = 0; n < DS; ++n) { hF[abase + n] = h[n]; Pg[abase + n] = P[n]; }
}

// ---------------------------------------------------------------------------
// Pass 2: per (b, d, n) combine chunk aggregates; hF <- chunk INITIAL state.
// ---------------------------------------------------------------------------
__global__ __launch_bounds__(256) void scan2_k(
    float* __restrict__ hF, const float* __restrict__ Pg)
{
  int gid = blockIdx.x * 256 + threadIdx.x;   // over B*DI*DS
  int b = gid / (DI * DS);
  int r = gid % (DI * DS);
  float carry = 0.f;
  for (int c = 0; c < NCH; ++c) {
    size_t idx = ((size_t)(b * NCH + c)) * (DI * DS) + r;
    float hf = hF[idx], p = Pg[idx];
    hF[idx] = carry;
    carry = fmaf(p, carry, hf);
  }
}

// ---------------------------------------------------------------------------
// Pass 3: rescan from h_in (dt fused); D-skip + z-gate; emit yz bf16.
// ---------------------------------------------------------------------------
__global__ __launch_bounds__(256) void scan3_k(
    const float* __restrict__ xconv, const float* __restrict__ xdbl,
    const float* __restrict__ Alog, const float* __restrict__ Wdt,
    const float* __restrict__ bdt, const float* __restrict__ hIn,
    const float* __restrict__ Dv, const float* __restrict__ z_in,
    ushort_t* __restrict__ yzb)
{
  int gid = blockIdx.x * 256 + threadIdx.x;   // over B*NCH*DI
  int d = gid % DI;
  int bc = gid / DI;
  int chunk = bc % NCH;
  int b = bc / NCH;

  float Ar[DS], Wc[DTR];
#pragma unroll
  for (int n = 0; n < DS; ++n) Ar[n] = -__expf(Alog[d * DS + n]);
#pragma unroll
  for (int k = 0; k < DTR; ++k) Wc[k] = Wdt[k * DI + d];
  float bd = bdt[d];
  float h[DS];
  size_t abase = (size_t)gid * DS;
#pragma unroll
  for (int n = 0; n < DS; ++n) h[n] = hIn[abase + n];
  float Dd = Dv[d];

  size_t base = ((size_t)b * L_SZ + (size_t)chunk * CHUNK) * DI + d;
  const float* xd = xdbl + ((size_t)b * L_SZ + (size_t)chunk * CHUNK) * 48;
  for (int t = 0; t < CHUNK; ++t) {
    const float* xr = xd + t * 48;
    float dta = bd;
#pragma unroll
    for (int k = 0; k < DTR; ++k) dta = fmaf(xr[k], Wc[k], dta);
    float dtv = softplus_f(dta);
    float u = xconv[base], zv = z_in[base];
    float du = dtv * u, y = 0.f;
#pragma unroll
    for (int n = 0; n < DS; ++n) {
      float dA = __expf(Ar[n] * dtv);
      h[n] = fmaf(h[n], dA, xr[DTR + n] * du);
      y = fmaf(xr[DTR + DS + n], h[n], y);
    }
    yzb[base] = f2bf((y + u * Dd) * zv);
    base += DI;
  }
}

// ---------------------------------------------------------------------------
extern "C" void kernel_launch(void* const* d_in, const int* in_sizes, int n_in,
                              void* d_out, int out_size, void* d_ws, size_t ws_size,
                              hipStream_t stream)
{
  const float* x      = (const float*)d_in[0];
  const float* W_in   = (const float*)d_in[1];
  const float* conv_w = (const float*)d_in[2];
  const float* conv_b = (const float*)d_in[3];
  const float* W_x    = (const float*)d_in[4];
  const float* W_dt   = (const float*)d_in[5];
  const float* b_dt   = (const float*)d_in[6];
  const float* A_log  = (const float*)d_in[7];
  const float* Dvec   = (const float*)d_in[8];
  const float* W_out  = (const float*)d_in[9];
  float* out = (float*)d_out;

  const size_t NBD  = (size_t)M_ROWS * DI;           // 6,291,456
  const size_t NAGG = (size_t)B_SZ * NCH * DI * DS;  // 1,572,864
  float* ws = (float*)d_ws;
  float* x_inner = ws;                 // [M, DI] fp32 (in_proj out; dead after conv)
  float* z_buf   = ws + NBD;           // silu(z)
  float* x_conv  = ws + 2 * NBD;       // [M, DI] fp32
  float* x_dbl   = ws + 3 * NBD;       // [M, 48] fp32
  float* hF      = x_dbl + (size_t)M_ROWS * 64;      // [B,NCH,DI,DS]
  float* Pg      = hF + NAGG;
  float* fend    = Pg + NAGG;
  ushort_t* xb     = (ushort_t*)fend;                      // [M, DM] bf16
  ushort_t* Wb_in  = xb    + (size_t)M_ROWS * DM;          // [2DI, DM] bf16 (W_in^T)
  ushort_t* Wb_out = Wb_in + (size_t)DM * 2 * DI;          // [DM, DI] bf16 (W_out^T)
  ushort_t* Wxb    = Wb_out + (size_t)DI * DM;             // [64, DI] bf16 (W_x^T pad)
  ushort_t* xcb    = Wxb + (size_t)64 * DI;                // [M, DI] bf16 x_conv
  // reuse of dead x_inner region after conv:
  ushort_t* yzb  = (ushort_t*)x_inner;                     // [M, DI] bf16 (12.6 MB)
  float* psum    = x_inner + NBD / 2;                      // [KSPLIT, M, 48] (6.3 MB)
  // total ws ~ 115 MB

  // 0) precision prep
  cvt4_k<<<(int)((size_t)M_ROWS * DM / 1024), 256, 0, stream>>>(x, xb);
  tcvt_k<<<dim3((2 * DI) / 32, DM / 32), 256, 0, stream>>>(W_in, Wb_in, DM, 2 * DI);
  tcvt_k<<<dim3(DM / 32, DI / 32), 256, 0, stream>>>(W_out, Wb_out, DI, DM);
  wxcvt_k<<<64 * DI / 256, 256, 0, stream>>>(W_x, Wxb);
  // 1) xz = x @ W_in ; split + silu(z)  [bf16 MFMA]
  mgemm_k<0><<<dim3((2 * DI) / 128, M_ROWS / 128), 256, 0, stream>>>(
      xb, Wb_in, x_inner, z_buf, M_ROWS, 2 * DI, DM);
  // 2) causal depthwise conv + bias + silu (fp32 + bf16 outputs)
  conv_silu_k<<<(int)(NBD / 1024), 256, 0, stream>>>(x_inner, conv_w, conv_b, x_conv, xcb);
  // 3) x_dbl = x_conv @ W_x  [bf16 MFMA, split-K 8 + reduce]
  xdbl_mfma_k<<<dim3(M_ROWS / 64, KSPLIT), 256, 0, stream>>>(xcb, Wxb, psum);
  xdbl_reduce_k<<<M_ROWS * 48 / 256, 256, 0, stream>>>(psum, x_dbl);
  // 4) chunked selective scan (3 passes, dt_proj fused); scan3 emits yz bf16
  scan1_k<<<B_SZ * NCH * DI / 256, 256, 0, stream>>>(
      x_conv, x_dbl, A_log, W_dt, b_dt, hF, Pg);
  scan2_k<<<B_SZ * DI * DS / 256, 256, 0, stream>>>(hF, Pg);
  scan3_k<<<B_SZ * NCH * DI / 256, 256, 0, stream>>>(
      x_conv, x_dbl, A_log, W_dt, b_dt, hF, Dvec, z_buf, yzb);
  // 5) out = yz @ W_out  [bf16 MFMA]
  mgemm_k<1><<<dim3(DM / 128, M_ROWS / 128), 256, 0, stream>>>(
      yzb, Wb_out, out, nullptr, M_ROWS, DM, DI);
}

// Round 6
// 300.421 us; speedup vs baseline: 6.0170x; 1.1908x over previous
//
#include <hip/hip_runtime.h>
#include <hip/hip_bf16.h>

// Problem constants (from reference)
#define B_SZ 2
#define L_SZ 2048
#define DM   768
#define DI   1536
#define DTR  16
#define DS   16
#define DC   4
#define M_ROWS (B_SZ * L_SZ)   // 4096
// chunked scan
#define CHUNK 32
#define NCH   (L_SZ / CHUNK)   // 64
#define KSPLIT 8
#define KSEG  (DI / KSPLIT)    // 192

typedef unsigned short ushort_t;
typedef __attribute__((ext_vector_type(8))) short bf16x8;   // 8 bf16 (4 VGPRs)
typedef __attribute__((ext_vector_type(4))) float f32x4;

static __device__ __forceinline__ float silu_f(float x) { return x / (1.f + __expf(-x)); }
static __device__ __forceinline__ float softplus_f(float x) {
  return x > 20.f ? x : log1pf(__expf(x));
}
static __device__ __forceinline__ ushort_t f2bf(float f) {   // RNE
  union { float f; unsigned u; } v; v.f = f;
  unsigned r = v.u + 0x7fffu + ((v.u >> 16) & 1u);
  return (ushort_t)(r >> 16);
}
static __device__ __forceinline__ float bfu2f(ushort_t u) {
  union { unsigned i; float f; } v; v.i = ((unsigned)u) << 16; return v.f;
}

// async global->LDS, 16 B per lane; LDS dest = wave-uniform base + lane*16
static __device__ __forceinline__ void gld16(const void* g, void* l) {
  __builtin_amdgcn_global_load_lds(
      (const __attribute__((address_space(1))) void*)g,
      (__attribute__((address_space(3))) void*)l, 16, 0, 0);
}

// ---------------------------------------------------------------------------
// bf16 MFMA GEMM (BT): C[M,N] = A[M,K] @ Bt[N,K]^T, A/Bt bf16 row-major.
// 128x128 tile, 256 thr = 4 waves (2x2), wave = 64x64 = 4x4 frags 16x16x32.
// EPI 0: split at col DI -> C0 = x_inner (fp32), C1 = silu(z) (fp32), stride DI
// EPI 1: C0 fp32, stride N
// ---------------------------------------------------------------------------
template <int EPI>
__global__ __launch_bounds__(256) void mgemm_k(
    const ushort_t* __restrict__ A, const ushort_t* __restrict__ Bt,
    float* __restrict__ C0, float* __restrict__ C1, int M, int N, int K)
{
  __shared__ ushort_t As[128 * 32];   // [row][k] 8 KB
  __shared__ ushort_t Bs[128 * 32];   // [col][k] 8 KB
  const int tid = threadIdx.x;
  const int lane = tid & 63;
  const int wave = tid >> 6;
  const int quad = lane >> 4, lr = lane & 15;
  const int wr = wave >> 1, wc = wave & 1;
  const int brow = blockIdx.y << 7, bcol = blockIdx.x << 7;

  f32x4 acc[4][4];
#pragma unroll
  for (int i = 0; i < 4; ++i)
#pragma unroll
    for (int j = 0; j < 4; ++j) acc[i][j] = (f32x4){0.f, 0.f, 0.f, 0.f};

  const int srow = tid >> 2;            // 0..63: tile row (first 64)
  const int sseg = (tid & 3) << 3;      // k offset 0,8,16,24

  for (int k0 = 0; k0 < K; k0 += 32) {
    const ushort_t* ga0 = A  + (size_t)(brow + srow)      * K + k0 + sseg;
    const ushort_t* ga1 = A  + (size_t)(brow + 64 + srow) * K + k0 + sseg;
    const ushort_t* gb0 = Bt + (size_t)(bcol + srow)      * K + k0 + sseg;
    const ushort_t* gb1 = Bt + (size_t)(bcol + 64 + srow) * K + k0 + sseg;
    gld16(ga0, &As[tid * 8]);
    gld16(ga1, &As[2048 + tid * 8]);
    gld16(gb0, &Bs[tid * 8]);
    gld16(gb1, &Bs[2048 + tid * 8]);
    __builtin_amdgcn_s_waitcnt(0);      // drain vmcnt (global_load_lds)
    __syncthreads();

    bf16x8 af[4], bf[4];
#pragma unroll
    for (int i = 0; i < 4; ++i)
      af[i] = *reinterpret_cast<const bf16x8*>(&As[(wr * 64 + i * 16 + lr) * 32 + quad * 8]);
#pragma unroll
    for (int j = 0; j < 4; ++j)
      bf[j] = *reinterpret_cast<const bf16x8*>(&Bs[(wc * 64 + j * 16 + lr) * 32 + quad * 8]);
#pragma unroll
    for (int i = 0; i < 4; ++i)
#pragma unroll
      for (int j = 0; j < 4; ++j)
        acc[i][j] = __builtin_amdgcn_mfma_f32_16x16x32_bf16(af[i], bf[j], acc[i][j], 0, 0, 0);
    __syncthreads();
  }

  // C/D layout: col = lane&15, row = quad*4 + reg  [verified m89/m91]
#pragma unroll
  for (int i = 0; i < 4; ++i) {
#pragma unroll
    for (int j = 0; j < 4; ++j) {
#pragma unroll
      for (int r = 0; r < 4; ++r) {
        int row = brow + wr * 64 + i * 16 + quad * 4 + r;
        int col = bcol + wc * 64 + j * 16 + lr;
        float v = acc[i][j][r];
        if (EPI == 0) {
          if (col < DI) C0[(size_t)row * DI + col] = v;
          else          C1[(size_t)row * DI + (col - DI)] = silu_f(v);
        } else {
          C0[(size_t)row * N + col] = v;
        }
      }
    }
  }
}

// ---------------------------------------------------------------------------
// fp32 -> bf16 convert (vectorized x4); n % 1024 == 0
// ---------------------------------------------------------------------------
__global__ __launch_bounds__(256) void cvt4_k(
    const float* __restrict__ in, ushort_t* __restrict__ out)
{
  int i = blockIdx.x * 256 + threadIdx.x;
  float4 v = reinterpret_cast<const float4*>(in)[i];
  ushort4 o;
  o.x = f2bf(v.x); o.y = f2bf(v.y); o.z = f2bf(v.z); o.w = f2bf(v.w);
  reinterpret_cast<ushort4*>(out)[i] = o;
}

// ---------------------------------------------------------------------------
// transpose + convert: T[c][r] = bf16(S[r][c]); R,C % 32 == 0
// ---------------------------------------------------------------------------
__global__ __launch_bounds__(256) void tcvt_k(
    const float* __restrict__ S, ushort_t* __restrict__ T, int R, int C)
{
  __shared__ float tile[32][33];
  const int c0 = blockIdx.x << 5, r0 = blockIdx.y << 5;
  const int tx = threadIdx.x & 31, ty = threadIdx.x >> 5;   // 32 x 8
  for (int rr = ty; rr < 32; rr += 8)
    tile[rr][tx] = S[(size_t)(r0 + rr) * C + c0 + tx];
  __syncthreads();
  for (int cc = ty; cc < 32; cc += 8)
    T[(size_t)(c0 + cc) * R + r0 + tx] = f2bf(tile[tx][cc]);
}

// ---------------------------------------------------------------------------
// W_x [DI,48] -> Wxb [64, DI] bf16 transposed, rows 48..63 zero
// ---------------------------------------------------------------------------
__global__ __launch_bounds__(256) void wxcvt_k(
    const float* __restrict__ Wx, ushort_t* __restrict__ Wxb)
{
  int gid = blockIdx.x * 256 + threadIdx.x;   // over 64*DI
  int k = gid % DI, n = gid / DI;
  Wxb[gid] = (n < 48) ? f2bf(Wx[(size_t)k * 48 + n]) : (ushort_t)0;
}

// ---------------------------------------------------------------------------
// Causal depthwise conv1d (k=4, left-pad 3, per-batch) + bias + silu.
// Vectorized x4 over d. Emits bf16 x_conv only (scan + x_dbl GEMM both use it).
// ---------------------------------------------------------------------------
__global__ __launch_bounds__(256) void conv_silu_k(
    const float* __restrict__ xin, const float* __restrict__ w,
    const float* __restrict__ bias, ushort_t* __restrict__ xcb)
{
  int idx = blockIdx.x * 256 + threadIdx.x;      // over B*L*DI/4
  int d4 = (idx % (DI / 4)) << 2;
  int bt = idx / (DI / 4);                       // b*L + t
  int t  = bt & (L_SZ - 1);
  float s[4];
  {
    float4 bv = *reinterpret_cast<const float4*>(&bias[d4]);
    s[0] = bv.x; s[1] = bv.y; s[2] = bv.z; s[3] = bv.w;
  }
  float wt[4][4];
#pragma unroll
  for (int c = 0; c < 4; ++c) {
    float4 wv = *reinterpret_cast<const float4*>(&w[(d4 + c) * DC]);
    wt[c][0] = wv.x; wt[c][1] = wv.y; wt[c][2] = wv.z; wt[c][3] = wv.w;
  }
#pragma unroll
  for (int k = 0; k < DC; ++k) {
    int tt = t - (DC - 1) + k;
    if (tt >= 0) {
      float4 xv = *reinterpret_cast<const float4*>(
          &xin[(size_t)(bt - (DC - 1) + k) * DI + d4]);
      s[0] = fmaf(wt[0][k], xv.x, s[0]);
      s[1] = fmaf(wt[1][k], xv.y, s[1]);
      s[2] = fmaf(wt[2][k], xv.z, s[2]);
      s[3] = fmaf(wt[3][k], xv.w, s[3]);
    }
  }
  ushort4 ob;
  ob.x = f2bf(silu_f(s[0])); ob.y = f2bf(silu_f(s[1]));
  ob.z = f2bf(silu_f(s[2])); ob.w = f2bf(silu_f(s[3]));
  reinterpret_cast<ushort4*>(xcb)[idx] = ob;
}

// ---------------------------------------------------------------------------
// x_dbl split-K MFMA: psum[split][M][48] = xcb[:, kseg] @ Wxb[0:48, kseg]^T
// ---------------------------------------------------------------------------
__global__ __launch_bounds__(256) void xdbl_mfma_k(
    const ushort_t* __restrict__ A, const ushort_t* __restrict__ Bt,
    float* __restrict__ psum)
{
  __shared__ ushort_t As[64 * 32];   // 4 KB: [row][k]
  __shared__ ushort_t Bs[64 * 32];   // 4 KB: [col][k] (cols 48..63 zero pad)
  const int tid = threadIdx.x, lane = tid & 63, wv = tid >> 6;
  const int quad = lane >> 4, lr = lane & 15;
  const int brow = blockIdx.x << 6;
  const int kbase = blockIdx.y * KSEG;

  f32x4 acc[3];
#pragma unroll
  for (int j = 0; j < 3; ++j) acc[j] = (f32x4){0.f, 0.f, 0.f, 0.f};

  const int srow = tid >> 2, sseg = (tid & 3) << 3;
  for (int k0 = 0; k0 < KSEG; k0 += 32) {
    gld16(A + (size_t)(brow + srow) * DI + kbase + k0 + sseg, &As[tid * 8]);
    gld16(Bt + (size_t)srow * DI + kbase + k0 + sseg, &Bs[tid * 8]);
    __builtin_amdgcn_s_waitcnt(0);
    __syncthreads();
    bf16x8 af = *reinterpret_cast<const bf16x8*>(&As[(wv * 16 + lr) * 32 + quad * 8]);
#pragma unroll
    for (int j = 0; j < 3; ++j) {
      bf16x8 bf = *reinterpret_cast<const bf16x8*>(&Bs[(j * 16 + lr) * 32 + quad * 8]);
      acc[j] = __builtin_amdgcn_mfma_f32_16x16x32_bf16(af, bf, acc[j], 0, 0, 0);
    }
    __syncthreads();
  }
#pragma unroll
  for (int j = 0; j < 3; ++j) {
#pragma unroll
    for (int r = 0; r < 4; ++r) {
      int row = brow + wv * 16 + quad * 4 + r;
      int col = j * 16 + lr;
      psum[((size_t)blockIdx.y * M_ROWS + row) * 48 + col] = acc[j][r];
    }
  }
}

__global__ __launch_bounds__(256) void xdbl_reduce_k(
    const float* __restrict__ psum, float* __restrict__ xdbl)
{
  int gid = blockIdx.x * 256 + threadIdx.x;   // over M*48
  float s = 0.f;
#pragma unroll
  for (int i = 0; i < KSPLIT; ++i) s += psum[(size_t)i * M_ROWS * 48 + gid];
  xdbl[gid] = s;
}

// ---------------------------------------------------------------------------
// Scan pass 1: per (b, chunk, d), scan from h0=0.
// dt = softplus(tree-dot(x_dbl[row,0:16], W_dt[:,d]) + b_dt[d]) computed ONCE,
// stored fp32 for scan3. Stores P[n] decay products + local final state hF[n].
// ---------------------------------------------------------------------------
__global__ __launch_bounds__(256) void scan1_k(
    const ushort_t* __restrict__ xcb, const float* __restrict__ xdbl,
    const float* __restrict__ Alog, const float* __restrict__ Wdt,
    const float* __restrict__ bdt, float* __restrict__ dt_out,
    float* __restrict__ hF, float* __restrict__ Pg)
{
  int gid = blockIdx.x * 256 + threadIdx.x;   // over B*NCH*DI
  int d = gid % DI;
  int bc = gid / DI;
  int chunk = bc % NCH;
  int b = bc / NCH;

  float Ar[DS], Wc[DTR];
#pragma unroll
  for (int n = 0; n < DS; ++n) Ar[n] = -__expf(Alog[d * DS + n]);
#pragma unroll
  for (int k = 0; k < DTR; ++k) Wc[k] = Wdt[k * DI + d];
  float bd = bdt[d];
  float h[DS], P[DS];
#pragma unroll
  for (int n = 0; n < DS; ++n) { h[n] = 0.f; P[n] = 1.f; }

  size_t base = ((size_t)b * L_SZ + (size_t)chunk * CHUNK) * DI + d;
  const float* xd = xdbl + ((size_t)b * L_SZ + (size_t)chunk * CHUNK) * 48;
  for (int t = 0; t < CHUNK; ++t) {
    const float* xr = xd + t * 48;
    float pr[DTR];
#pragma unroll
    for (int k = 0; k < DTR; ++k) pr[k] = xr[k] * Wc[k];
#pragma unroll
    for (int s = DTR / 2; s > 0; s >>= 1)
#pragma unroll
      for (int k = 0; k < DTR; ++k) if (k < s) pr[k] += pr[k + s];
    float dtv = softplus_f(bd + pr[0]);
    dt_out[base] = dtv;
    float u = bfu2f(xcb[base]);
    float du = dtv * u;
#pragma unroll
    for (int n = 0; n < DS; ++n) {
      float dA = __expf(Ar[n] * dtv);
      h[n] = fmaf(h[n], dA, xr[DTR + n] * du);
      P[n] *= dA;
    }
    base += DI;
  }
  size_t abase = (size_t)gid * DS;
#pragma unroll
  for (int n = 0; n < DS; ++n) { hF[abase + n] = h[n]; Pg[abase + n] = P[n]; }
}

// ---------------------------------------------------------------------------
// Pass 2: per (b, d, n) combine chunk aggregates; hF <- chunk INITIAL state.
// ---------------------------------------------------------------------------
__global__ __launch_bounds__(256) void scan2_k(
    float* __restrict__ hF, const float* __restrict__ Pg)
{
  int gid = blockIdx.x * 256 + threadIdx.x;   // over B*DI*DS
  int b = gid / (DI * DS);
  int r = gid % (DI * DS);
  float carry = 0.f;
  for (int c = 0; c < NCH; ++c) {
    size_t idx = ((size_t)(b * NCH + c)) * (DI * DS) + r;
    float hf = hF[idx], p = Pg[idx];
    hF[idx] = carry;
    carry = fmaf(p, carry, hf);
  }
}

// ---------------------------------------------------------------------------
// Pass 3: rescan from h_in (dt streamed from scan1); D-skip + z-gate; yz bf16.
// ---------------------------------------------------------------------------
__global__ __launch_bounds__(256) void scan3_k(
    const ushort_t* __restrict__ xcb, const float* __restrict__ dtb,
    const float* __restrict__ xdbl, const float* __restrict__ Alog,
    const float* __restrict__ hIn, const float* __restrict__ Dv,
    const float* __restrict__ z_in, ushort_t* __restrict__ yzb)
{
  int gid = blockIdx.x * 256 + threadIdx.x;   // over B*NCH*DI
  int d = gid % DI;
  int bc = gid / DI;
  int chunk = bc % NCH;
  int b = bc / NCH;

  float Ar[DS];
#pragma unroll
  for (int n = 0; n < DS; ++n) Ar[n] = -__expf(Alog[d * DS + n]);
  float h[DS];
  size_t abase = (size_t)gid * DS;
#pragma unroll
  for (int n = 0; n < DS; ++n) h[n] = hIn[abase + n];
  float Dd = Dv[d];

  size_t base = ((size_t)b * L_SZ + (size_t)chunk * CHUNK) * DI + d;
  const float* xd = xdbl + ((size_t)b * L_SZ + (size_t)chunk * CHUNK) * 48;
  for (int t = 0; t < CHUNK; ++t) {
    const float* xr = xd + t * 48;
    float dtv = dtb[base];
    float u = bfu2f(xcb[base]), zv = z_in[base];
    float du = dtv * u, y = 0.f;
#pragma unroll
    for (int n = 0; n < DS; ++n) {
      float dA = __expf(Ar[n] * dtv);
      h[n] = fmaf(h[n], dA, xr[DTR + n] * du);
      y = fmaf(xr[DTR + DS + n], h[n], y);
    }
    yzb[base] = f2bf((y + u * Dd) * zv);
    base += DI;
  }
}

// ---------------------------------------------------------------------------
extern "C" void kernel_launch(void* const* d_in, const int* in_sizes, int n_in,
                              void* d_out, int out_size, void* d_ws, size_t ws_size,
                              hipStream_t stream)
{
  const float* x      = (const float*)d_in[0];
  const float* W_in   = (const float*)d_in[1];
  const float* conv_w = (const float*)d_in[2];
  const float* conv_b = (const float*)d_in[3];
  const float* W_x    = (const float*)d_in[4];
  const float* W_dt   = (const float*)d_in[5];
  const float* b_dt   = (const float*)d_in[6];
  const float* A_log  = (const float*)d_in[7];
  const float* Dvec   = (const float*)d_in[8];
  const float* W_out  = (const float*)d_in[9];
  float* out = (float*)d_out;

  const size_t NBD  = (size_t)M_ROWS * DI;           // 6,291,456
  const size_t NAGG = (size_t)B_SZ * NCH * DI * DS;  // 3,145,728 (CHUNK=32)
  float* ws = (float*)d_ws;
  float* x_inner = ws;                 // [M, DI] fp32 (in_proj out; dead after conv)
  float* z_buf   = ws + NBD;           // silu(z) fp32
  float* dt_buf  = ws + 2 * NBD;       // [M, DI] fp32 dt (was x_conv)
  float* x_dbl   = ws + 3 * NBD;       // [M, 48] fp32 (rows padded to 64 alloc)
  float* hF      = x_dbl + (size_t)M_ROWS * 64;      // [B,NCH,DI,DS]
  float* Pg      = hF + NAGG;
  float* fend    = Pg + NAGG;
  ushort_t* xb     = (ushort_t*)fend;                      // [M, DM] bf16
  ushort_t* Wb_in  = xb    + (size_t)M_ROWS * DM;          // [2DI, DM] bf16 (W_in^T)
  ushort_t* Wb_out = Wb_in + (size_t)DM * 2 * DI;          // [DM, DI] bf16 (W_out^T)
  ushort_t* Wxb    = Wb_out + (size_t)DI * DM;             // [64, DI] bf16 (W_x^T pad)
  ushort_t* xcb    = Wxb + (size_t)64 * DI;                // [M, DI] bf16 x_conv
  // reuse of dead x_inner region after conv:
  ushort_t* yzb  = (ushort_t*)x_inner;                     // [M, DI] bf16 (12.6 MB)
  float* psum    = x_inner + NBD / 2;                      // [KSPLIT, M, 48] (6.3 MB)
  // total ws ~ 128 MB

  // 0) precision prep
  cvt4_k<<<(int)((size_t)M_ROWS * DM / 1024), 256, 0, stream>>>(x, xb);
  tcvt_k<<<dim3((2 * DI) / 32, DM / 32), 256, 0, stream>>>(W_in, Wb_in, DM, 2 * DI);
  tcvt_k<<<dim3(DM / 32, DI / 32), 256, 0, stream>>>(W_out, Wb_out, DI, DM);
  wxcvt_k<<<64 * DI / 256, 256, 0, stream>>>(W_x, Wxb);
  // 1) xz = x @ W_in ; split + silu(z)  [bf16 MFMA]
  mgemm_k<0><<<dim3((2 * DI) / 128, M_ROWS / 128), 256, 0, stream>>>(
      xb, Wb_in, x_inner, z_buf, M_ROWS, 2 * DI, DM);
  // 2) causal depthwise conv + bias + silu (bf16 out)
  conv_silu_k<<<(int)(NBD / 1024), 256, 0, stream>>>(x_inner, conv_w, conv_b, xcb);
  // 3) x_dbl = x_conv @ W_x  [bf16 MFMA, split-K 8 + reduce]
  xdbl_mfma_k<<<dim3(M_ROWS / 64, KSPLIT), 256, 0, stream>>>(xcb, Wxb, psum);
  xdbl_reduce_k<<<M_ROWS * 48 / 256, 256, 0, stream>>>(psum, x_dbl);
  // 4) chunked selective scan (3 passes); dt computed once in pass 1
  scan1_k<<<B_SZ * NCH * DI / 256, 256, 0, stream>>>(
      xcb, x_dbl, A_log, W_dt, b_dt, dt_buf, hF, Pg);
  scan2_k<<<B_SZ * DI * DS / 256, 256, 0, stream>>>(hF, Pg);
  scan3_k<<<B_SZ * NCH * DI / 256, 256, 0, stream>>>(
      xcb, dt_buf, x_dbl, A_log, hF, Dvec, z_buf, yzb);
  // 5) out = yz @ W_out  [bf16 MFMA]
  mgemm_k<1><<<dim3(DM / 128, M_ROWS / 128), 256, 0, stream>>>(
      yzb, Wb_out, out, nullptr, M_ROWS, DM, DI);
}